// Round 8
// baseline (6896.280 us; speedup 1.0000x reference)
//
#include <hip/hip_runtime.h>
#include <stdint.h>
#include <math.h>

typedef unsigned int u32;
typedef unsigned long long u64;
typedef double d4 __attribute__((ext_vector_type(4)));

#define NPX    3800        // 50*76
#define NANCH  34200       // NPX*9
#define NSEL   6000
#define NOUT   300

// ---- workspace layout (bytes) ----
#define OFF_T      0ull
#define OFF_WT     124518400ull
#define OFF_BOXES  (OFF_WT + 9437184ull)
#define OFF_ITEMS  (OFF_BOXES + 4377600ull)
#define OFF_PART   (OFF_ITEMS + 2188800ull + 192000ull)
#define WS_NEED_SPLIT (OFF_PART + 43776000ull)

// ============================================================
// Kernel 0: weight transpose conv_w[co][ci][ky][kx] -> wt[kk][ci][co]
// ============================================================
__global__ __launch_bounds__(1024) void wtrans_kernel(const float* __restrict__ cw,
                                                      float* __restrict__ wt) {
    int o = blockIdx.x * 1024 + threadIdx.x;
    if (o >= 512*512*9) return;
    int co = o & 511;
    int ci = (o >> 9) & 511;
    int kk = o >> 18;
    wt[o] = cw[((co << 9) + ci) * 9 + kk];
}

// ============================================================
// Kernel 1: 3x3 conv 512->512 + bias + ReLU via f64 MFMA
// Round-8 structure: ZERO LDS, ZERO barriers. Both A and B fragments
// are lane-linear in global memory, so each wave double-buffers them
// straight into registers (24 f32 loads in flight under 32 MFMAs =
// 2048 matrix-pipe cycles). B traffic is 4x block-shared staging but
// L1/L2-resident (FETCH was at 8% HBM). Accumulation order identical
// to round 7 -> bit-identical t. D lane->coord map PROBED at runtime
// (f64 C/D layout on this HW is not the documented one -- rounds 3/4).
// ============================================================
__global__ __launch_bounds__(256, 3) void conv3x3_mfma_kernel(const float* __restrict__ feat,
                                                              const float* __restrict__ wt,
                                                              const float* __restrict__ bias,
                                                              double* __restrict__ t) {
    const int b   = blockIdx.z;
    const int co0 = blockIdx.y << 7;
    const int px0 = blockIdx.x << 6;
    const int tid = threadIdx.x;
    const int w    = tid >> 6;
    const int l    = tid & 63;
    const int quad = l >> 4;
    const int lc   = l & 15;

    // ---- runtime D-layout probe ----
    int rr[4], cc[4];
    {
        d4 pzr = {0.0, 0.0, 0.0, 0.0};
        d4 pzc = {0.0, 0.0, 0.0, 0.0};
        double paM = (double)lc;
        double pbN = (double)lc;
        pzr = __builtin_amdgcn_mfma_f64_16x16x4f64(paM, 1.0, pzr, 0, 0, 0);
        pzc = __builtin_amdgcn_mfma_f64_16x16x4f64(1.0, pbN, pzc, 0, 0, 0);
        #pragma unroll
        for (int g = 0; g < 4; ++g) {
            rr[g] = (((int)pzr[g]) >> 2) & 15;
            cc[g] = (((int)pzc[g]) >> 2) & 15;
        }
    }

    d4 acc[2][4];
    #pragma unroll
    for (int i = 0; i < 2; ++i)
        #pragma unroll
        for (int j = 0; j < 4; ++j) acc[i][j] = (d4){0.0, 0.0, 0.0, 0.0};

    const float* featb = feat + (size_t)b * 512 * NPX;

    // per-nt pixel geometry (fixed for whole kernel)
    int pyv[4], pxv[4]; bool pv[4];
    #pragma unroll
    for (int nt = 0; nt < 4; ++nt) {
        int p  = px0 + (nt << 4) + lc;
        int py = p / 76;
        pyv[nt] = py; pxv[nt] = p - py * 76; pv[nt] = (p < NPX);
    }

    // A: lane l holds A[m=lc][k=quad] of frag (ks,mt):
    //    wt[kk][ci0 + 4ks + quad][co0 + w*32 + mt*16 + lc]
    const float* abase = wt + ((size_t)quad << 9) + co0 + (w << 5) + lc;

    float vaf[8], vbf[16];

    auto loadA = [&](int q, float* va) {
        int kk  = q >> 5;
        int ci0 = (q & 31) << 4;
        const float* ap = abase + ((size_t)(kk * 512 + ci0) << 9);
        #pragma unroll
        for (int ks = 0; ks < 4; ++ks) {
            va[ks * 2 + 0] = ap[(ks << 11)];        // mt=0 (4 ci rows * 512 co)
            va[ks * 2 + 1] = ap[(ks << 11) + 16];   // mt=1
        }
    };
    // B: lane l holds B[k=quad][n=lc] of frag (ks,nt):
    //    feat[ci0 + 4ks + quad][pix(nt) + halo(kk)]
    auto loadB = [&](int q, float* vb) {
        int kk  = q >> 5;
        int ci0 = (q & 31) << 4;
        int kd  = kk / 3;
        int dy  = kd - 1, dx = kk - kd * 3 - 1;
        const float* brow = featb + (size_t)(ci0 + quad) * NPX;
        #pragma unroll
        for (int nt = 0; nt < 4; ++nt) {
            int iy = pyv[nt] + dy, ix = pxv[nt] + dx;
            bool ok = pv[nt] && ((unsigned)iy < 50u) && ((unsigned)ix < 76u);
            const float* bp = brow + iy * 76 + ix;
            #pragma unroll
            for (int ks = 0; ks < 4; ++ks)
                vb[ks * 4 + nt] = ok ? bp[(size_t)(ks << 2) * NPX] : 0.0f;
        }
    };

    double a_cur[8], b_cur[16];
    loadA(0, vaf); loadB(0, vbf);
    #pragma unroll
    for (int j = 0; j < 8; ++j)  a_cur[j] = (double)vaf[j];
    #pragma unroll
    for (int j = 0; j < 16; ++j) b_cur[j] = (double)vbf[j];

    for (int q = 0; q < 288; ++q) {
        if (q < 287) { loadA(q + 1, vaf); loadB(q + 1, vbf); }  // in flight under MFMA
        #pragma unroll
        for (int ks = 0; ks < 4; ++ks) {
            double a0 = a_cur[ks * 2], a1 = a_cur[ks * 2 + 1];
            #pragma unroll
            for (int nt = 0; nt < 4; ++nt) {
                double bv = b_cur[ks * 4 + nt];
                acc[0][nt] = __builtin_amdgcn_mfma_f64_16x16x4f64(a0, bv, acc[0][nt], 0, 0, 0);
                acc[1][nt] = __builtin_amdgcn_mfma_f64_16x16x4f64(a1, bv, acc[1][nt], 0, 0, 0);
            }
        }
        if (q < 287) {
            #pragma unroll
            for (int j = 0; j < 8; ++j)  a_cur[j] = (double)vaf[j];
            #pragma unroll
            for (int j = 0; j < 16; ++j) b_cur[j] = (double)vbf[j];
        }
    }

    // epilogue: bias + ReLU, store f64, indexed by PROBED (rr,cc)
    #pragma unroll
    for (int mt = 0; mt < 2; ++mt) {
        #pragma unroll
        for (int g = 0; g < 4; ++g) {
            int co = co0 + (w << 5) + (mt << 4) + rr[g];
            double bs = (double)bias[co];
            double* row = t + ((size_t)b * 512 + co) * NPX;
            #pragma unroll
            for (int nt = 0; nt < 4; ++nt) {
                int pp = px0 + (nt << 4) + cc[g];
                if (pp < NPX) {
                    double v = acc[mt][nt][g] + bs;
                    row[pp] = v > 0.0 ? v : 0.0;
                }
            }
        }
    }
}

// ============================================================
// Kernel 2a: 1x1 heads, split-K x4 partials (f64)
// ============================================================
__global__ __launch_bounds__(64) void heads_partial_kernel(const double* __restrict__ t,
                                                           const float* __restrict__ cls_w,
                                                           const float* __restrict__ box_w,
                                                           double* __restrict__ part) {
    const int b = blockIdx.y, c = blockIdx.z;
    const int p = blockIdx.x * 64 + threadIdx.x;
    if (p >= NPX) return;
    const double* tb = t + ((size_t)b * 512 + c * 128) * NPX + p;

    double ac[9]  = {};
    double ab[36] = {};
    for (int ci = 0; ci < 128; ++ci) {
        double tv = tb[(size_t)ci * NPX];
        int cw = c * 128 + ci;
        #pragma unroll
        for (int o = 0; o < 9;  ++o) ac[o] = fma((double)cls_w[o * 512 + cw], tv, ac[o]);
        #pragma unroll
        for (int o = 0; o < 36; ++o) ab[o] = fma((double)box_w[o * 512 + cw], tv, ab[o]);
    }
    double* dst = part + ((size_t)(c * 8 + b) * 45) * NPX + p;
    #pragma unroll
    for (int o = 0; o < 9;  ++o) dst[(size_t)o * NPX] = ac[o];
    #pragma unroll
    for (int o = 0; o < 36; ++o) dst[(size_t)(9 + o) * NPX] = ab[o];
}

// shared decode body
__device__ __forceinline__ void decode_px(int b, int p, const double* s45,
                                          const float* cls_b, const float* box_b,
                                          float* out_obj, float* out_del,
                                          float* boxes, u64* items) {
    float* ob = out_obj + (size_t)b * NANCH + (size_t)p * 9;
    float* dl = out_del + (size_t)b * NANCH * 4 + (size_t)p * 36;
    const int yy = p / 76, xx = p - yy * 76;

    #pragma unroll
    for (int a = 0; a < 9; ++a) {
        double s  = s45[a] + (double)cls_b[a];
        ob[a] = (float)s;
        double d0 = s45[9 + 4*a + 0] + (double)box_b[4*a+0];
        double d1 = s45[9 + 4*a + 1] + (double)box_b[4*a+1];
        double d2 = s45[9 + 4*a + 2] + (double)box_b[4*a+2];
        double d3 = s45[9 + 4*a + 3] + (double)box_b[4*a+3];
        dl[4*a+0] = (float)d0; dl[4*a+1] = (float)d1;
        dl[4*a+2] = (float)d2; dl[4*a+3] = (float)d3;

        int si = a / 3, ri = a - si * 3;
        double sz = (si == 0) ? 128.0 : ((si == 1) ? 256.0 : 512.0);
        double hr = (ri == 0) ? 0.7071067811865476 : ((ri == 1) ? 1.0 : 1.4142135623730951);
        float bx2f = (float)(sz / hr * 0.5);
        float by2f = (float)(sz * hr * 0.5);

        double sx = (double)(xx * 16), sy = (double)(yy * 16);
        double x1 = sx - (double)bx2f, x2 = sx + (double)bx2f;
        double y1 = sy - (double)by2f, y2 = sy + (double)by2f;

        double wa = x2 - x1, ha = y2 - y1;
        double cxa = x1 + 0.5 * wa, cya = y1 + 0.5 * ha;
        double cx = d0 * wa + cxa, cy = d1 * ha + cya;
        double w  = exp(d2) * wa,  h  = exp(d3) * ha;

        double px1 = cx - 0.5 * w, py1 = cy - 0.5 * h;
        double px2 = cx + 0.5 * w, py2 = cy + 0.5 * h;
        px1 = fmin(fmax(px1, 0.0), 1216.0);
        py1 = fmin(fmax(py1, 0.0), 800.0);
        px2 = fmin(fmax(px2, 0.0), 1216.0);
        py2 = fmin(fmax(py2, 0.0), 800.0);

        bool keep = ((px2 - px1) >= 16.0) && ((py2 - py1) >= 16.0);
        double se = keep ? s : -INFINITY;

        u64 ubits = (u64)__double_as_longlong(se);
        u64 ka = (ubits >> 63) ? ~ubits : (ubits | 0x8000000000000000ull);
        u64 kd = ~ka;
        int n = p * 9 + a;
        items[(size_t)b * NANCH + n] = (kd & ~0xFFFFull) | (u64)(u32)n;
        *(float4*)(boxes + ((size_t)b * NANCH + n) * 4) =
            make_float4((float)px1, (float)py1, (float)px2, (float)py2);
    }
}

// ============================================================
// Kernel 2b: reduce partials (c ascending, deterministic) + decode
// ============================================================
__global__ __launch_bounds__(64) void reduce_decode_kernel(const double* __restrict__ part,
                                                           const float* __restrict__ cls_b,
                                                           const float* __restrict__ box_b,
                                                           float* __restrict__ out_obj,
                                                           float* __restrict__ out_del,
                                                           float* __restrict__ boxes,
                                                           u64* __restrict__ items) {
    const int b = blockIdx.y;
    const int p = blockIdx.x * 64 + threadIdx.x;
    if (p >= NPX) return;
    double s45[45];
    #pragma unroll
    for (int o = 0; o < 45; ++o) {
        double s = part[((size_t)(0 * 8 + b) * 45 + o) * NPX + p];
        s += part[((size_t)(1 * 8 + b) * 45 + o) * NPX + p];
        s += part[((size_t)(2 * 8 + b) * 45 + o) * NPX + p];
        s += part[((size_t)(3 * 8 + b) * 45 + o) * NPX + p];
        s45[o] = s;
    }
    decode_px(b, p, s45, cls_b, box_b, out_obj, out_del, boxes, items);
}

// ============================================================
// Kernel 2-fallback: single-stage heads+decode (if ws too small)
// ============================================================
__global__ __launch_bounds__(256) void heads_decode_kernel(const double* __restrict__ t,
                                                           const float* __restrict__ cls_w,
                                                           const float* __restrict__ cls_b,
                                                           const float* __restrict__ box_w,
                                                           const float* __restrict__ box_b,
                                                           float* __restrict__ out_obj,
                                                           float* __restrict__ out_del,
                                                           float* __restrict__ boxes,
                                                           u64* __restrict__ items) {
    const int b = blockIdx.y;
    const int p = blockIdx.x * 256 + threadIdx.x;
    if (p >= NPX) return;
    const double* tb = t + (size_t)b * 512 * NPX + p;
    double s45[45];
    #pragma unroll
    for (int o = 0; o < 45; ++o) s45[o] = 0.0;
    for (int ci = 0; ci < 512; ++ci) {
        double tv = tb[(size_t)ci * NPX];
        #pragma unroll
        for (int o = 0; o < 9;  ++o) s45[o]     = fma((double)cls_w[o * 512 + ci], tv, s45[o]);
        #pragma unroll
        for (int o = 0; o < 36; ++o) s45[9 + o] = fma((double)box_w[o * 512 + ci], tv, s45[9 + o]);
    }
    decode_px(b, p, s45, cls_b, box_b, out_obj, out_del, boxes, items);
}

// ============================================================
// IoU > 0.7 test (f32, matches reference formula)
// ============================================================
__device__ __forceinline__ bool iou_gt(float4 A, float4 B, float areaA, float areaB) {
    float ix1 = fmaxf(A.x, B.x), iy1 = fmaxf(A.y, B.y);
    float ix2 = fminf(A.z, B.z), iy2 = fminf(A.w, B.w);
    float iw = fmaxf(ix2 - ix1, 0.0f), ih = fmaxf(iy2 - iy1, 0.0f);
    float inter = iw * ih;
    float uni = areaA + areaB - inter;
    float iou = (uni > 0.0f) ? (inter / uni) : 0.0f;
    return iou > 0.7f;
}

// ============================================================
// Kernel 3: fused top-6000 select + bitonic sort + serial-scan NMS
// ============================================================
__global__ __launch_bounds__(1024) void topk_nms_kernel(const u64* __restrict__ items,
                                                        const float* __restrict__ boxes,
                                                        float* __restrict__ out) {
    extern __shared__ u64 buf[];              // 8192 u64
    u32* hist = (u32*)buf;
    u32* scan = hist + 4096;
    u32* scal = hist + 5120;

    const int b   = blockIdx.x;
    const int tid = threadIdx.x;
    const u64* it = items + (size_t)b * NANCH;

    // ---- level-1 histogram on item bits 52..63
    #pragma unroll
    for (int i = 0; i < 4; ++i) hist[tid * 4 + i] = 0;
    __syncthreads();
    for (int i = tid; i < NANCH; i += 1024)
        atomicAdd(&hist[(u32)(it[i] >> 52)], 1);
    __syncthreads();

    u32 B1, cum1;
    {
        u32 c0 = hist[tid*4], c1 = hist[tid*4+1], c2 = hist[tid*4+2], c3 = hist[tid*4+3];
        u32 S = c0 + c1 + c2 + c3;
        scan[tid] = S;
        __syncthreads();
        for (int off = 1; off < 1024; off <<= 1) {
            u32 v = (tid >= off) ? scan[tid - off] : 0;
            __syncthreads();
            scan[tid] += v;
            __syncthreads();
        }
        u32 excl = scan[tid] - S;
        const u32 target = 5999;
        if (target >= excl && target < excl + S) {
            u32 pfx = excl, bidx, cum;
            if      (target < pfx + c0)           { bidx = tid*4;   cum = pfx; }
            else if (target < pfx + c0 + c1)      { bidx = tid*4+1; cum = pfx + c0; }
            else if (target < pfx + c0 + c1 + c2) { bidx = tid*4+2; cum = pfx + c0 + c1; }
            else                                  { bidx = tid*4+3; cum = pfx + c0 + c1 + c2; }
            scal[0] = bidx; scal[1] = cum;
        }
    }
    __syncthreads();
    B1 = scal[0]; cum1 = scal[1];
    __syncthreads();

    // ---- level-2 histogram on item bits 40..51, within bin B1
    #pragma unroll
    for (int i = 0; i < 4; ++i) hist[tid * 4 + i] = 0;
    __syncthreads();
    for (int i = tid; i < NANCH; i += 1024) {
        u64 v = it[i];
        if ((u32)(v >> 52) == B1)
            atomicAdd(&hist[(u32)(v >> 40) & 0xFFF], 1);
    }
    __syncthreads();

    u32 B2;
    {
        u32 c0 = hist[tid*4], c1 = hist[tid*4+1], c2 = hist[tid*4+2], c3 = hist[tid*4+3];
        u32 S = c0 + c1 + c2 + c3;
        scan[tid] = S;
        __syncthreads();
        for (int off = 1; off < 1024; off <<= 1) {
            u32 v = (tid >= off) ? scan[tid - off] : 0;
            __syncthreads();
            scan[tid] += v;
            __syncthreads();
        }
        u32 excl = scan[tid] - S;
        const u32 target = 5999 - cum1;
        if (target >= excl && target < excl + S) {
            u32 pfx = excl, bidx;
            if      (target < pfx + c0)           bidx = tid*4;
            else if (target < pfx + c0 + c1)      bidx = tid*4+1;
            else if (target < pfx + c0 + c1 + c2) bidx = tid*4+2;
            else                                  bidx = tid*4+3;
            scal[2] = bidx;
        }
    }
    __syncthreads();
    B2 = scal[2];
    const u32 T = ((B1 << 12) | B2) + 1;
    __syncthreads();

    // ---- compaction (pad = ~0)
    for (int i = tid; i < 8192; i += 1024) buf[i] = ~0ull;
    __syncthreads();
    u32* cnt = (u32*)&buf[8191];
    if (tid == 0) *cnt = 0;
    __syncthreads();
    for (int i = tid; i < NANCH; i += 1024) {
        u64 v = it[i];
        if ((u32)(v >> 40) < T) {
            u32 pos = atomicAdd(cnt, 1);
            if (pos < 8191) buf[pos] = v;
        }
    }
    __syncthreads();
    if (tid == 0) buf[8191] = ~0ull;
    __syncthreads();

    // ---- bitonic sort 8192 u64 ascending (keys unique -> deterministic)
    for (int size = 2; size <= 8192; size <<= 1) {
        for (int stride = size >> 1; stride > 0; stride >>= 1) {
            #pragma unroll
            for (int v = 0; v < 4; ++v) {
                int idx = tid + (v << 10);
                int i = 2 * idx - (idx & (stride - 1));
                int j = i + stride;
                bool up = ((i & size) == 0);
                u64 x = buf[i], y = buf[j];
                if ((x > y) == up) { buf[i] = y; buf[j] = x; }
            }
            __syncthreads();
        }
    }

    // ---- pull my 6 chunk-candidates into registers
    float4 bx6[6]; u32 dead6[6];
    #pragma unroll
    for (int s = 0; s < 6; ++s) {
        int r = tid + (s << 10);
        u64 v = buf[r];
        bool dd = (r >= NSEL) || ((u32)(v >> 32) >= 0xFFF00000u);
        float4 bb = make_float4(0.f, 0.f, 0.f, 0.f);
        if (!dd) {
            u32 n = (u32)(v & 0xFFFFull);
            bb = *(const float4*)(boxes + ((size_t)b * NANCH + n) * 4);
        }
        bx6[s] = bb;
        dead6[s] = dd ? 1u : 0u;
    }
    __syncthreads();   // done with sorted buf -> reuse as NMS scratch

    float4* candbox = (float4*)buf;            // [1024]
    u64*    wmask   = (u64*)(buf + 2560);      // [16]
    float4* accb    = (float4*)(buf + 3072);   // [304]
    u32*    cntp    = (u32*)(buf + 3712);
    if (tid == 0) *cntp = 0;
    __syncthreads();

    // ---- serial-scan greedy NMS (accept iff no earlier accept IoU>0.7)
    for (int s = 0; s < 6; ++s) {
        int count = (int)*cntp;                // uniform
        if (count >= NOUT) break;
        float4 mb = bx6[s];
        float  ma = (mb.z - mb.x) * (mb.w - mb.y);
        bool dd = dead6[s] != 0;
        for (int a2 = 0; a2 < count && !dd; ++a2) {
            float4 abx = accb[a2];             // broadcast read
            if (iou_gt(mb, abx, ma, (abx.z - abx.x) * (abx.w - abx.y))) dd = true;
        }
        candbox[tid] = mb;
        u64 bal = __ballot(!dd);
        if ((tid & 63) == 0) wmask[tid >> 6] = bal;
        __syncthreads();
        if (tid < 64) {                        // wave 0 serializes survivors in rank order
            int cnt2 = count;
            for (int w2 = 0; w2 < 16 && cnt2 < NOUT; ++w2) {
                u64 mm = wmask[w2];
                while (mm != 0 && cnt2 < NOUT) {
                    int bit = __ffsll(mm) - 1;
                    mm &= (mm - 1);
                    float4 cb = candbox[(w2 << 6) + bit];
                    float  ca = (cb.z - cb.x) * (cb.w - cb.y);
                    bool okc = true;
                    for (int base = count; base < cnt2 && okc; base += 64) {
                        int idx = base + tid;
                        bool bad = false;
                        if (idx < cnt2) {
                            float4 abx = accb[idx];
                            bad = iou_gt(cb, abx, ca, (abx.z - abx.x) * (abx.w - abx.y));
                        }
                        if (__any(bad)) okc = false;
                    }
                    if (okc) {
                        if (tid == 0) accb[cnt2] = cb;
                        cnt2++;
                    }
                }
            }
            if (tid == 0) *cntp = (u32)cnt2;
        }
        __syncthreads();
    }

    int fin = (int)*cntp;
    for (int r = tid; r < NOUT; r += 1024) {
        float4 v = (r < fin) ? accb[r] : make_float4(0.f, 0.f, 0.f, 0.f);
        *(float4*)(out + ((size_t)b * NOUT + r) * 4) = v;
    }
}

// ============================================================
extern "C" void kernel_launch(void* const* d_in, const int* in_sizes, int n_in,
                              void* d_out, int out_size, void* d_ws, size_t ws_size,
                              hipStream_t stream) {
    const float* feat   = (const float*)d_in[0];
    const float* conv_w = (const float*)d_in[1];
    const float* conv_b = (const float*)d_in[2];
    const float* cls_w  = (const float*)d_in[3];
    const float* cls_b  = (const float*)d_in[4];
    const float* box_w  = (const float*)d_in[5];
    const float* box_b  = (const float*)d_in[6];

    float* out       = (float*)d_out;
    float* out_props = out;                       // [8][300][4]
    float* out_obj   = out + 9600;                // [8][34200]
    float* out_del   = out + 9600 + 273600;       // [8][34200][4]

    char* ws = (char*)d_ws;
    double* t      = (double*)(ws + OFF_T);
    float*  wt     = (float*)(ws + OFF_WT);
    float*  boxes  = (float*)(ws + OFF_BOXES);
    u64*    items  = (u64*)(ws + OFF_ITEMS);
    double* part   = (double*)(ws + OFF_PART);

    hipLaunchKernelGGL(wtrans_kernel, dim3(2304), dim3(1024), 0, stream, conv_w, wt);
    hipLaunchKernelGGL(conv3x3_mfma_kernel, dim3(60, 4, 8), dim3(256), 0, stream,
                       feat, wt, conv_b, t);
    if (ws_size >= WS_NEED_SPLIT) {
        hipLaunchKernelGGL(heads_partial_kernel, dim3(60, 8, 4), dim3(64), 0, stream,
                           t, cls_w, box_w, part);
        hipLaunchKernelGGL(reduce_decode_kernel, dim3(60, 8), dim3(64), 0, stream,
                           part, cls_b, box_b, out_obj, out_del, boxes, items);
    } else {
        hipLaunchKernelGGL(heads_decode_kernel, dim3(15, 8), dim3(256), 0, stream,
                           t, cls_w, cls_b, box_w, box_b, out_obj, out_del, boxes, items);
    }
    hipLaunchKernelGGL(topk_nms_kernel, dim3(8), dim3(1024), 65536, stream,
                       items, boxes, out_props);
}

// Round 9
// 3116.843 us; speedup vs baseline: 2.2126x; 2.2126x over previous
//
#include <hip/hip_runtime.h>
#include <stdint.h>
#include <math.h>

typedef unsigned int u32;
typedef unsigned long long u64;
typedef double d4 __attribute__((ext_vector_type(4)));

#define NPX    3800        // 50*76
#define NANCH  34200       // NPX*9
#define NSEL   6000
#define NOUT   300

// ---- workspace layout (bytes) ----
#define OFF_T      0ull
#define OFF_WT     124518400ull
#define OFF_BOXES  (OFF_WT + 9437184ull)
#define OFF_ITEMS  (OFF_BOXES + 4377600ull)
#define OFF_PART   (OFF_ITEMS + 2188800ull + 192000ull)
#define WS_NEED_SPLIT (OFF_PART + 43776000ull)

// ============================================================
// Kernel 0: weight transpose conv_w[co][ci][ky][kx] -> wt[kk][ci][co]
// ============================================================
__global__ __launch_bounds__(1024) void wtrans_kernel(const float* __restrict__ cw,
                                                      float* __restrict__ wt) {
    int o = blockIdx.x * 1024 + threadIdx.x;
    if (o >= 512*512*9) return;
    int co = o & 511;
    int ci = (o >> 9) & 511;
    int kk = o >> 18;
    wt[o] = cw[((co << 9) + ci) * 9 + kk];
}

// ============================================================
// Kernel 1: 3x3 conv 512->512 + bias + ReLU via f64 MFMA
// Round-9: zero-LDS zero-barrier (round-8 concept) with the scratch
// bug fixed: prefetch buffers stay f32 (cvt at MFMA-use), no lambdas /
// pointer-passed arrays (macros expand inline; SROA-safe), 2x-unrolled
// chunk loop with role-swapped register sets. kk-phase loop rolled.
// B pointers clamped in-bounds + multiplicative mask (no OOB selects).
// D lane->coord map PROBED at runtime (f64 C/D layout on this HW is
// not the documented one -- rounds 3/4 proved it).
// ============================================================
__global__ __launch_bounds__(256, 3) void conv3x3_mfma_kernel(const float* __restrict__ feat,
                                                              const float* __restrict__ wt,
                                                              const float* __restrict__ bias,
                                                              double* __restrict__ t) {
    const int b   = blockIdx.z;
    const int co0 = blockIdx.y << 7;
    const int px0 = blockIdx.x << 6;
    const int tid = threadIdx.x;
    const int w    = tid >> 6;
    const int l    = tid & 63;
    const int quad = l >> 4;
    const int lc   = l & 15;

    // ---- runtime D-layout probe ----
    int rr[4], cc[4];
    {
        d4 pzr = {0.0, 0.0, 0.0, 0.0};
        d4 pzc = {0.0, 0.0, 0.0, 0.0};
        double paM = (double)lc;
        double pbN = (double)lc;
        pzr = __builtin_amdgcn_mfma_f64_16x16x4f64(paM, 1.0, pzr, 0, 0, 0);
        pzc = __builtin_amdgcn_mfma_f64_16x16x4f64(1.0, pbN, pzc, 0, 0, 0);
        #pragma unroll
        for (int g = 0; g < 4; ++g) {
            rr[g] = (((int)pzr[g]) >> 2) & 15;
            cc[g] = (((int)pzc[g]) >> 2) & 15;
        }
    }

    d4 acc[2][4];
    #pragma unroll
    for (int i = 0; i < 2; ++i)
        #pragma unroll
        for (int j = 0; j < 4; ++j) acc[i][j] = (d4){0.0, 0.0, 0.0, 0.0};

    const float* featb = feat + (size_t)b * 512 * NPX;
    // A: lane l holds A[m=lc][k=quad] of frag (ks,mt):
    //    wt[kk][ci0+4ks+quad][co0 + w*32 + mt*16 + lc]
    const float* abase = wt + ((size_t)quad << 9) + co0 + (w << 5) + lc;

    // fixed per-nt pixel geometry
    int pyv0, pyv1, pyv2, pyv3, pxv0, pxv1, pxv2, pxv3;
    bool pvd0, pvd1, pvd2, pvd3;
    {
        int p0 = px0 + lc,      p1 = px0 + 16 + lc;
        int p2 = px0 + 32 + lc, p3 = px0 + 48 + lc;
        pyv0 = p0 / 76; pxv0 = p0 - pyv0 * 76; pvd0 = p0 < NPX;
        pyv1 = p1 / 76; pxv1 = p1 - pyv1 * 76; pvd1 = p1 < NPX;
        pyv2 = p2 / 76; pxv2 = p2 - pyv2 * 76; pvd2 = p2 < NPX;
        pyv3 = p3 / 76; pxv3 = p3 - pyv3 * 76; pvd3 = p3 < NPX;
    }

    float a0[8], b0[16], a1[8], b1[16];

// load chunk m_ of the current kk-phase into register sets A_/B_
#define LOADC(A_, B_, m_) do {                                                  \
    const float* ap_ = aph + ((size_t)(m_) << 13);                              \
    _Pragma("unroll")                                                           \
    for (int ks_ = 0; ks_ < 4; ++ks_) {                                         \
        A_[ks_*2+0] = ap_[(ks_ << 11)];                                         \
        A_[ks_*2+1] = ap_[(ks_ << 11) + 16];                                    \
    }                                                                           \
    {                                                                           \
        const float* q0_ = bb0 + (size_t)((m_) << 4) * NPX;                     \
        const float* q1_ = bb1 + (size_t)((m_) << 4) * NPX;                     \
        const float* q2_ = bb2 + (size_t)((m_) << 4) * NPX;                     \
        const float* q3_ = bb3 + (size_t)((m_) << 4) * NPX;                     \
        _Pragma("unroll")                                                       \
        for (int ks_ = 0; ks_ < 4; ++ks_) {                                     \
            size_t o_ = (size_t)(ks_ << 2) * NPX;                               \
            B_[ks_*4+0] = q0_[o_] * mk0;                                        \
            B_[ks_*4+1] = q1_[o_] * mk1;                                        \
            B_[ks_*4+2] = q2_[o_] * mk2;                                        \
            B_[ks_*4+3] = q3_[o_] * mk3;                                        \
        }                                                                       \
    }                                                                           \
} while (0)

#define MFMAC(A_, B_) do {                                                      \
    _Pragma("unroll")                                                           \
    for (int ks_ = 0; ks_ < 4; ++ks_) {                                         \
        double A0_ = (double)A_[ks_*2], A1_ = (double)A_[ks_*2+1];              \
        _Pragma("unroll")                                                       \
        for (int nt_ = 0; nt_ < 4; ++nt_) {                                     \
            double Bv_ = (double)B_[ks_*4+nt_];                                 \
            acc[0][nt_] = __builtin_amdgcn_mfma_f64_16x16x4f64(A0_, Bv_, acc[0][nt_], 0, 0, 0); \
            acc[1][nt_] = __builtin_amdgcn_mfma_f64_16x16x4f64(A1_, Bv_, acc[1][nt_], 0, 0, 0); \
        }                                                                       \
    }                                                                           \
} while (0)

    for (int kk = 0; kk < 9; ++kk) {
        const int kd = kk / 3;
        const int dy = kd - 1, dx = kk - kd * 3 - 1;
        const float* aph = abase + ((size_t)kk << 18);

        // per-nt clamped B base (always in-bounds) + multiplicative mask
        int iy0 = pyv0 + dy, ix0 = pxv0 + dx;
        int iy1 = pyv1 + dy, ix1 = pxv1 + dx;
        int iy2 = pyv2 + dy, ix2 = pxv2 + dx;
        int iy3 = pyv3 + dy, ix3 = pxv3 + dx;
        bool ok0 = pvd0 && ((unsigned)iy0 < 50u) && ((unsigned)ix0 < 76u);
        bool ok1 = pvd1 && ((unsigned)iy1 < 50u) && ((unsigned)ix1 < 76u);
        bool ok2 = pvd2 && ((unsigned)iy2 < 50u) && ((unsigned)ix2 < 76u);
        bool ok3 = pvd3 && ((unsigned)iy3 < 50u) && ((unsigned)ix3 < 76u);
        const float* brow = featb + (size_t)quad * NPX;
        const float* bb0 = brow + (ok0 ? (iy0 * 76 + ix0) : 0);
        const float* bb1 = brow + (ok1 ? (iy1 * 76 + ix1) : 0);
        const float* bb2 = brow + (ok2 ? (iy2 * 76 + ix2) : 0);
        const float* bb3 = brow + (ok3 ? (iy3 * 76 + ix3) : 0);
        const float mk0 = ok0 ? 1.0f : 0.0f;
        const float mk1 = ok1 ? 1.0f : 0.0f;
        const float mk2 = ok2 ? 1.0f : 0.0f;
        const float mk3 = ok3 ? 1.0f : 0.0f;

        LOADC(a0, b0, 0);
        for (int m = 0; m < 32; m += 2) {
            LOADC(a1, b1, m + 1);          // in flight under MFMAC(a0,b0)
            MFMAC(a0, b0);
            if (m + 2 < 32) LOADC(a0, b0, m + 2);   // in flight under MFMAC(a1,b1)
            MFMAC(a1, b1);
        }
    }
#undef LOADC
#undef MFMAC

    // epilogue: bias + ReLU, store f64, indexed by PROBED (rr,cc)
    #pragma unroll
    for (int mt = 0; mt < 2; ++mt) {
        #pragma unroll
        for (int g = 0; g < 4; ++g) {
            int co = co0 + (w << 5) + (mt << 4) + rr[g];
            double bs = (double)bias[co];
            double* row = t + ((size_t)b * 512 + co) * NPX;
            #pragma unroll
            for (int nt = 0; nt < 4; ++nt) {
                int pp = px0 + (nt << 4) + cc[g];
                if (pp < NPX) {
                    double v = acc[mt][nt][g] + bs;
                    row[pp] = v > 0.0 ? v : 0.0;
                }
            }
        }
    }
}

// ============================================================
// Kernel 2a: 1x1 heads, split-K x4 partials (f64)
// ============================================================
__global__ __launch_bounds__(64) void heads_partial_kernel(const double* __restrict__ t,
                                                           const float* __restrict__ cls_w,
                                                           const float* __restrict__ box_w,
                                                           double* __restrict__ part) {
    const int b = blockIdx.y, c = blockIdx.z;
    const int p = blockIdx.x * 64 + threadIdx.x;
    if (p >= NPX) return;
    const double* tb = t + ((size_t)b * 512 + c * 128) * NPX + p;

    double ac[9]  = {};
    double ab[36] = {};
    for (int ci = 0; ci < 128; ++ci) {
        double tv = tb[(size_t)ci * NPX];
        int cw = c * 128 + ci;
        #pragma unroll
        for (int o = 0; o < 9;  ++o) ac[o] = fma((double)cls_w[o * 512 + cw], tv, ac[o]);
        #pragma unroll
        for (int o = 0; o < 36; ++o) ab[o] = fma((double)box_w[o * 512 + cw], tv, ab[o]);
    }
    double* dst = part + ((size_t)(c * 8 + b) * 45) * NPX + p;
    #pragma unroll
    for (int o = 0; o < 9;  ++o) dst[(size_t)o * NPX] = ac[o];
    #pragma unroll
    for (int o = 0; o < 36; ++o) dst[(size_t)(9 + o) * NPX] = ab[o];
}

// shared decode body
__device__ __forceinline__ void decode_px(int b, int p, const double* s45,
                                          const float* cls_b, const float* box_b,
                                          float* out_obj, float* out_del,
                                          float* boxes, u64* items) {
    float* ob = out_obj + (size_t)b * NANCH + (size_t)p * 9;
    float* dl = out_del + (size_t)b * NANCH * 4 + (size_t)p * 36;
    const int yy = p / 76, xx = p - yy * 76;

    #pragma unroll
    for (int a = 0; a < 9; ++a) {
        double s  = s45[a] + (double)cls_b[a];
        ob[a] = (float)s;
        double d0 = s45[9 + 4*a + 0] + (double)box_b[4*a+0];
        double d1 = s45[9 + 4*a + 1] + (double)box_b[4*a+1];
        double d2 = s45[9 + 4*a + 2] + (double)box_b[4*a+2];
        double d3 = s45[9 + 4*a + 3] + (double)box_b[4*a+3];
        dl[4*a+0] = (float)d0; dl[4*a+1] = (float)d1;
        dl[4*a+2] = (float)d2; dl[4*a+3] = (float)d3;

        int si = a / 3, ri = a - si * 3;
        double sz = (si == 0) ? 128.0 : ((si == 1) ? 256.0 : 512.0);
        double hr = (ri == 0) ? 0.7071067811865476 : ((ri == 1) ? 1.0 : 1.4142135623730951);
        float bx2f = (float)(sz / hr * 0.5);
        float by2f = (float)(sz * hr * 0.5);

        double sx = (double)(xx * 16), sy = (double)(yy * 16);
        double x1 = sx - (double)bx2f, x2 = sx + (double)bx2f;
        double y1 = sy - (double)by2f, y2 = sy + (double)by2f;

        double wa = x2 - x1, ha = y2 - y1;
        double cxa = x1 + 0.5 * wa, cya = y1 + 0.5 * ha;
        double cx = d0 * wa + cxa, cy = d1 * ha + cya;
        double w  = exp(d2) * wa,  h  = exp(d3) * ha;

        double px1 = cx - 0.5 * w, py1 = cy - 0.5 * h;
        double px2 = cx + 0.5 * w, py2 = cy + 0.5 * h;
        px1 = fmin(fmax(px1, 0.0), 1216.0);
        py1 = fmin(fmax(py1, 0.0), 800.0);
        px2 = fmin(fmax(px2, 0.0), 1216.0);
        py2 = fmin(fmax(py2, 0.0), 800.0);

        bool keep = ((px2 - px1) >= 16.0) && ((py2 - py1) >= 16.0);
        double se = keep ? s : -INFINITY;

        u64 ubits = (u64)__double_as_longlong(se);
        u64 ka = (ubits >> 63) ? ~ubits : (ubits | 0x8000000000000000ull);
        u64 kd = ~ka;
        int n = p * 9 + a;
        items[(size_t)b * NANCH + n] = (kd & ~0xFFFFull) | (u64)(u32)n;
        *(float4*)(boxes + ((size_t)b * NANCH + n) * 4) =
            make_float4((float)px1, (float)py1, (float)px2, (float)py2);
    }
}

// ============================================================
// Kernel 2b: reduce partials (c ascending, deterministic) + decode
// ============================================================
__global__ __launch_bounds__(64) void reduce_decode_kernel(const double* __restrict__ part,
                                                           const float* __restrict__ cls_b,
                                                           const float* __restrict__ box_b,
                                                           float* __restrict__ out_obj,
                                                           float* __restrict__ out_del,
                                                           float* __restrict__ boxes,
                                                           u64* __restrict__ items) {
    const int b = blockIdx.y;
    const int p = blockIdx.x * 64 + threadIdx.x;
    if (p >= NPX) return;
    double s45[45];
    #pragma unroll
    for (int o = 0; o < 45; ++o) {
        double s = part[((size_t)(0 * 8 + b) * 45 + o) * NPX + p];
        s += part[((size_t)(1 * 8 + b) * 45 + o) * NPX + p];
        s += part[((size_t)(2 * 8 + b) * 45 + o) * NPX + p];
        s += part[((size_t)(3 * 8 + b) * 45 + o) * NPX + p];
        s45[o] = s;
    }
    decode_px(b, p, s45, cls_b, box_b, out_obj, out_del, boxes, items);
}

// ============================================================
// Kernel 2-fallback: single-stage heads+decode (if ws too small)
// ============================================================
__global__ __launch_bounds__(256) void heads_decode_kernel(const double* __restrict__ t,
                                                           const float* __restrict__ cls_w,
                                                           const float* __restrict__ cls_b,
                                                           const float* __restrict__ box_w,
                                                           const float* __restrict__ box_b,
                                                           float* __restrict__ out_obj,
                                                           float* __restrict__ out_del,
                                                           float* __restrict__ boxes,
                                                           u64* __restrict__ items) {
    const int b = blockIdx.y;
    const int p = blockIdx.x * 256 + threadIdx.x;
    if (p >= NPX) return;
    const double* tb = t + (size_t)b * 512 * NPX + p;
    double s45[45];
    #pragma unroll
    for (int o = 0; o < 45; ++o) s45[o] = 0.0;
    for (int ci = 0; ci < 512; ++ci) {
        double tv = tb[(size_t)ci * NPX];
        #pragma unroll
        for (int o = 0; o < 9;  ++o) s45[o]     = fma((double)cls_w[o * 512 + ci], tv, s45[o]);
        #pragma unroll
        for (int o = 0; o < 36; ++o) s45[9 + o] = fma((double)box_w[o * 512 + ci], tv, s45[9 + o]);
    }
    decode_px(b, p, s45, cls_b, box_b, out_obj, out_del, boxes, items);
}

// ============================================================
// IoU > 0.7 test (f32, matches reference formula)
// ============================================================
__device__ __forceinline__ bool iou_gt(float4 A, float4 B, float areaA, float areaB) {
    float ix1 = fmaxf(A.x, B.x), iy1 = fmaxf(A.y, B.y);
    float ix2 = fminf(A.z, B.z), iy2 = fminf(A.w, B.w);
    float iw = fmaxf(ix2 - ix1, 0.0f), ih = fmaxf(iy2 - iy1, 0.0f);
    float inter = iw * ih;
    float uni = areaA + areaB - inter;
    float iou = (uni > 0.0f) ? (inter / uni) : 0.0f;
    return iou > 0.7f;
}

// ============================================================
// Kernel 3: fused top-6000 select + bitonic sort + serial-scan NMS
// ============================================================
__global__ __launch_bounds__(1024) void topk_nms_kernel(const u64* __restrict__ items,
                                                        const float* __restrict__ boxes,
                                                        float* __restrict__ out) {
    extern __shared__ u64 buf[];              // 8192 u64
    u32* hist = (u32*)buf;
    u32* scan = hist + 4096;
    u32* scal = hist + 5120;

    const int b   = blockIdx.x;
    const int tid = threadIdx.x;
    const u64* it = items + (size_t)b * NANCH;

    // ---- level-1 histogram on item bits 52..63
    #pragma unroll
    for (int i = 0; i < 4; ++i) hist[tid * 4 + i] = 0;
    __syncthreads();
    for (int i = tid; i < NANCH; i += 1024)
        atomicAdd(&hist[(u32)(it[i] >> 52)], 1);
    __syncthreads();

    u32 B1, cum1;
    {
        u32 c0 = hist[tid*4], c1 = hist[tid*4+1], c2 = hist[tid*4+2], c3 = hist[tid*4+3];
        u32 S = c0 + c1 + c2 + c3;
        scan[tid] = S;
        __syncthreads();
        for (int off = 1; off < 1024; off <<= 1) {
            u32 v = (tid >= off) ? scan[tid - off] : 0;
            __syncthreads();
            scan[tid] += v;
            __syncthreads();
        }
        u32 excl = scan[tid] - S;
        const u32 target = 5999;
        if (target >= excl && target < excl + S) {
            u32 pfx = excl, bidx, cum;
            if      (target < pfx + c0)           { bidx = tid*4;   cum = pfx; }
            else if (target < pfx + c0 + c1)      { bidx = tid*4+1; cum = pfx + c0; }
            else if (target < pfx + c0 + c1 + c2) { bidx = tid*4+2; cum = pfx + c0 + c1; }
            else                                  { bidx = tid*4+3; cum = pfx + c0 + c1 + c2; }
            scal[0] = bidx; scal[1] = cum;
        }
    }
    __syncthreads();
    B1 = scal[0]; cum1 = scal[1];
    __syncthreads();

    // ---- level-2 histogram on item bits 40..51, within bin B1
    #pragma unroll
    for (int i = 0; i < 4; ++i) hist[tid * 4 + i] = 0;
    __syncthreads();
    for (int i = tid; i < NANCH; i += 1024) {
        u64 v = it[i];
        if ((u32)(v >> 52) == B1)
            atomicAdd(&hist[(u32)(v >> 40) & 0xFFF], 1);
    }
    __syncthreads();

    u32 B2;
    {
        u32 c0 = hist[tid*4], c1 = hist[tid*4+1], c2 = hist[tid*4+2], c3 = hist[tid*4+3];
        u32 S = c0 + c1 + c2 + c3;
        scan[tid] = S;
        __syncthreads();
        for (int off = 1; off < 1024; off <<= 1) {
            u32 v = (tid >= off) ? scan[tid - off] : 0;
            __syncthreads();
            scan[tid] += v;
            __syncthreads();
        }
        u32 excl = scan[tid] - S;
        const u32 target = 5999 - cum1;
        if (target >= excl && target < excl + S) {
            u32 pfx = excl, bidx;
            if      (target < pfx + c0)           bidx = tid*4;
            else if (target < pfx + c0 + c1)      bidx = tid*4+1;
            else if (target < pfx + c0 + c1 + c2) bidx = tid*4+2;
            else                                  bidx = tid*4+3;
            scal[2] = bidx;
        }
    }
    __syncthreads();
    B2 = scal[2];
    const u32 T = ((B1 << 12) | B2) + 1;
    __syncthreads();

    // ---- compaction (pad = ~0)
    for (int i = tid; i < 8192; i += 1024) buf[i] = ~0ull;
    __syncthreads();
    u32* cnt = (u32*)&buf[8191];
    if (tid == 0) *cnt = 0;
    __syncthreads();
    for (int i = tid; i < NANCH; i += 1024) {
        u64 v = it[i];
        if ((u32)(v >> 40) < T) {
            u32 pos = atomicAdd(cnt, 1);
            if (pos < 8191) buf[pos] = v;
        }
    }
    __syncthreads();
    if (tid == 0) buf[8191] = ~0ull;
    __syncthreads();

    // ---- bitonic sort 8192 u64 ascending (keys unique -> deterministic)
    for (int size = 2; size <= 8192; size <<= 1) {
        for (int stride = size >> 1; stride > 0; stride >>= 1) {
            #pragma unroll
            for (int v = 0; v < 4; ++v) {
                int idx = tid + (v << 10);
                int i = 2 * idx - (idx & (stride - 1));
                int j = i + stride;
                bool up = ((i & size) == 0);
                u64 x = buf[i], y = buf[j];
                if ((x > y) == up) { buf[i] = y; buf[j] = x; }
            }
            __syncthreads();
        }
    }

    // ---- pull my 6 chunk-candidates into registers
    float4 bx6[6]; u32 dead6[6];
    #pragma unroll
    for (int s = 0; s < 6; ++s) {
        int r = tid + (s << 10);
        u64 v = buf[r];
        bool dd = (r >= NSEL) || ((u32)(v >> 32) >= 0xFFF00000u);
        float4 bb = make_float4(0.f, 0.f, 0.f, 0.f);
        if (!dd) {
            u32 n = (u32)(v & 0xFFFFull);
            bb = *(const float4*)(boxes + ((size_t)b * NANCH + n) * 4);
        }
        bx6[s] = bb;
        dead6[s] = dd ? 1u : 0u;
    }
    __syncthreads();   // done with sorted buf -> reuse as NMS scratch

    float4* candbox = (float4*)buf;            // [1024]
    u64*    wmask   = (u64*)(buf + 2560);      // [16]
    float4* accb    = (float4*)(buf + 3072);   // [304]
    u32*    cntp    = (u32*)(buf + 3712);
    if (tid == 0) *cntp = 0;
    __syncthreads();

    // ---- serial-scan greedy NMS (accept iff no earlier accept IoU>0.7)
    for (int s = 0; s < 6; ++s) {
        int count = (int)*cntp;                // uniform
        if (count >= NOUT) break;
        float4 mb = bx6[s];
        float  ma = (mb.z - mb.x) * (mb.w - mb.y);
        bool dd = dead6[s] != 0;
        for (int a2 = 0; a2 < count && !dd; ++a2) {
            float4 abx = accb[a2];             // broadcast read
            if (iou_gt(mb, abx, ma, (abx.z - abx.x) * (abx.w - abx.y))) dd = true;
        }
        candbox[tid] = mb;
        u64 bal = __ballot(!dd);
        if ((tid & 63) == 0) wmask[tid >> 6] = bal;
        __syncthreads();
        if (tid < 64) {                        // wave 0 serializes survivors in rank order
            int cnt2 = count;
            for (int w2 = 0; w2 < 16 && cnt2 < NOUT; ++w2) {
                u64 mm = wmask[w2];
                while (mm != 0 && cnt2 < NOUT) {
                    int bit = __ffsll(mm) - 1;
                    mm &= (mm - 1);
                    float4 cb = candbox[(w2 << 6) + bit];
                    float  ca = (cb.z - cb.x) * (cb.w - cb.y);
                    bool okc = true;
                    for (int base = count; base < cnt2 && okc; base += 64) {
                        int idx = base + tid;
                        bool bad = false;
                        if (idx < cnt2) {
                            float4 abx = accb[idx];
                            bad = iou_gt(cb, abx, ca, (abx.z - abx.x) * (abx.w - abx.y));
                        }
                        if (__any(bad)) okc = false;
                    }
                    if (okc) {
                        if (tid == 0) accb[cnt2] = cb;
                        cnt2++;
                    }
                }
            }
            if (tid == 0) *cntp = (u32)cnt2;
        }
        __syncthreads();
    }

    int fin = (int)*cntp;
    for (int r = tid; r < NOUT; r += 1024) {
        float4 v = (r < fin) ? accb[r] : make_float4(0.f, 0.f, 0.f, 0.f);
        *(float4*)(out + ((size_t)b * NOUT + r) * 4) = v;
    }
}

// ============================================================
extern "C" void kernel_launch(void* const* d_in, const int* in_sizes, int n_in,
                              void* d_out, int out_size, void* d_ws, size_t ws_size,
                              hipStream_t stream) {
    const float* feat   = (const float*)d_in[0];
    const float* conv_w = (const float*)d_in[1];
    const float* conv_b = (const float*)d_in[2];
    const float* cls_w  = (const float*)d_in[3];
    const float* cls_b  = (const float*)d_in[4];
    const float* box_w  = (const float*)d_in[5];
    const float* box_b  = (const float*)d_in[6];

    float* out       = (float*)d_out;
    float* out_props = out;                       // [8][300][4]
    float* out_obj   = out + 9600;                // [8][34200]
    float* out_del   = out + 9600 + 273600;       // [8][34200][4]

    char* ws = (char*)d_ws;
    double* t      = (double*)(ws + OFF_T);
    float*  wt     = (float*)(ws + OFF_WT);
    float*  boxes  = (float*)(ws + OFF_BOXES);
    u64*    items  = (u64*)(ws + OFF_ITEMS);
    double* part   = (double*)(ws + OFF_PART);

    hipLaunchKernelGGL(wtrans_kernel, dim3(2304), dim3(1024), 0, stream, conv_w, wt);
    hipLaunchKernelGGL(conv3x3_mfma_kernel, dim3(60, 4, 8), dim3(256), 0, stream,
                       feat, wt, conv_b, t);
    if (ws_size >= WS_NEED_SPLIT) {
        hipLaunchKernelGGL(heads_partial_kernel, dim3(60, 8, 4), dim3(64), 0, stream,
                           t, cls_w, box_w, part);
        hipLaunchKernelGGL(reduce_decode_kernel, dim3(60, 8), dim3(64), 0, stream,
                           part, cls_b, box_b, out_obj, out_del, boxes, items);
    } else {
        hipLaunchKernelGGL(heads_decode_kernel, dim3(15, 8), dim3(256), 0, stream,
                           t, cls_w, cls_b, box_w, box_b, out_obj, out_del, boxes, items);
    }
    hipLaunchKernelGGL(topk_nms_kernel, dim3(8), dim3(1024), 65536, stream,
                       items, boxes, out_props);
}

// Round 10
// 2928.563 us; speedup vs baseline: 2.3548x; 1.0643x over previous
//
#include <hip/hip_runtime.h>
#include <stdint.h>
#include <math.h>

typedef unsigned int u32;
typedef unsigned long long u64;
typedef double d4 __attribute__((ext_vector_type(4)));

#define NPX    3800        // 50*76
#define NANCH  34200       // NPX*9
#define NSEL   6000
#define NOUT   300

// ---- workspace layout (bytes) ----
#define OFF_T      0ull
#define OFF_WT     124518400ull
#define OFF_BOXES  (OFF_WT + 9437184ull)
#define OFF_ITEMS  (OFF_BOXES + 4377600ull)
#define OFF_PART   (OFF_ITEMS + 2188800ull + 192000ull)
#define WS_NEED_SPLIT (OFF_PART + 43776000ull)

// ============================================================
// Kernel 0: weight transpose conv_w[co][ci][ky][kx] -> wt[kk][ci][co]
// ============================================================
__global__ __launch_bounds__(1024) void wtrans_kernel(const float* __restrict__ cw,
                                                      float* __restrict__ wt) {
    int o = blockIdx.x * 1024 + threadIdx.x;
    if (o >= 512*512*9) return;
    int co = o & 511;
    int ci = (o >> 9) & 511;
    int kk = o >> 18;
    wt[o] = cw[((co << 9) + ci) * 9 + kk];
}

// ============================================================
// Kernel 1: 3x3 conv 512->512 + bias + ReLU via f64 MFMA
// Round-10 = round-7 proven structure (A direct global->reg, B
// ping-pong LDS, ONE barrier/iter) + occupancy push:
//   - B staged as f32 in LDS (8 KB ping-pong vs 16 KB), cvt at use
//   - A prefetch kept f32, cvt at use (exact; acc order unchanged)
//   - __launch_bounds__(256,4): more resident blocks/CU so other
//     blocks' MFMAs fill this block's barrier drain (m114 lever).
// D lane->coord map PROBED at runtime (f64 C/D layout on this HW is
// not the documented one -- rounds 3/4 proved it).
// ============================================================
__global__ __launch_bounds__(256, 4) void conv3x3_mfma_kernel(const float* __restrict__ feat,
                                                              const float* __restrict__ wt,
                                                              const float* __restrict__ bias,
                                                              double* __restrict__ t) {
    const int b   = blockIdx.z;
    const int co0 = blockIdx.y << 7;
    const int px0 = blockIdx.x << 6;
    const int tid = threadIdx.x;
    const int w    = tid >> 6;
    const int l    = tid & 63;
    const int quad = l >> 4;
    const int lc   = l & 15;

    __shared__ float BsF[2][1024];   // 8 KB ping-pong: 16 frags x 64 lanes, f32

    // ---- runtime D-layout probe ----
    int rr[4], cc[4];
    {
        d4 pzr = {0.0, 0.0, 0.0, 0.0};
        d4 pzc = {0.0, 0.0, 0.0, 0.0};
        double paM = (double)lc;
        double pbN = (double)lc;
        pzr = __builtin_amdgcn_mfma_f64_16x16x4f64(paM, 1.0, pzr, 0, 0, 0);
        pzc = __builtin_amdgcn_mfma_f64_16x16x4f64(1.0, pbN, pzc, 0, 0, 0);
        #pragma unroll
        for (int g = 0; g < 4; ++g) {
            rr[g] = (((int)pzr[g]) >> 2) & 15;
            cc[g] = (((int)pzc[g]) >> 2) & 15;
        }
    }

    d4 acc[2][4];
    #pragma unroll
    for (int i = 0; i < 2; ++i)
        #pragma unroll
        for (int j = 0; j < 4; ++j) acc[i][j] = (d4){0.0, 0.0, 0.0, 0.0};

    const float* featb = feat + (size_t)b * 512 * NPX;

    // B staging geometry (HW-verified rounds 6/7):
    //  thread stages ci_local = 4j + b_quad at pixel b_pxl into slot tid + j*256
    const int b_quad = (tid >> 4) & 3;
    const int b_pxl  = ((tid >> 6) << 4) | (tid & 15);
    const int p      = px0 + b_pxl;
    const int py     = p / 76;
    const int px     = p - py * 76;
    const bool pvalid = (p < NPX);

    float vaf[8], vbf[4];
    float a_cur[8];

    // A fragment (ks,mt), lane l: wt[kk][ci0 + 4ks + quad][co0 + w*32 + mt*16 + lc]
    auto loadA = [&](int q, float* va) {
        int kk  = q >> 5;
        int ci0 = (q & 31) << 4;
        const float* ap = wt + (((size_t)(kk * 512 + ci0 + quad)) << 9)
                             + co0 + (w << 5) + lc;
        #pragma unroll
        for (int ks = 0; ks < 4; ++ks) {
            va[ks * 2 + 0] = ap[(ks << 11)];        // mt=0 (4 ci rows * 512 co)
            va[ks * 2 + 1] = ap[(ks << 11) + 16];   // mt=1
        }
    };
    auto loadB = [&](int q, float* vb) {
        int kk  = q >> 5;
        int ci0 = (q & 31) << 4;
        int kd = kk / 3;
        int dy = kd - 1, dx = kk - kd * 3 - 1;
        int iy = py + dy, ix = px + dx;
        bool ok = pvalid && ((unsigned)iy < 50u) && ((unsigned)ix < 76u);
        if (ok) {
            const float* bp = featb + (size_t)(ci0 + b_quad) * NPX + iy * 76 + ix;
            #pragma unroll
            for (int j = 0; j < 4; ++j) vb[j] = bp[(size_t)(j << 2) * NPX];
        } else {
            vb[0] = vb[1] = vb[2] = vb[3] = 0.0f;
        }
    };

    // prologue
    loadA(0, vaf); loadB(0, vbf);
    #pragma unroll
    for (int j = 0; j < 4; ++j) BsF[0][tid + (j << 8)] = vbf[j];
    #pragma unroll
    for (int j = 0; j < 8; ++j) a_cur[j] = vaf[j];
    __syncthreads();

    for (int q = 0; q < 288; ++q) {
        const int cur = q & 1;
        if (q < 287) { loadA(q + 1, vaf); loadB(q + 1, vbf); }   // in flight under MFMA
        const float* bb = BsF[cur];
        #pragma unroll
        for (int ks = 0; ks < 4; ++ks) {
            const float* bp = bb + (ks << 8);                    // frag (ks,nt=0)
            double a0 = (double)a_cur[ks * 2], a1 = (double)a_cur[ks * 2 + 1];
            #pragma unroll
            for (int nt = 0; nt < 4; ++nt) {
                double bv = (double)bp[(nt << 6) + l];
                acc[0][nt] = __builtin_amdgcn_mfma_f64_16x16x4f64(a0, bv, acc[0][nt], 0, 0, 0);
                acc[1][nt] = __builtin_amdgcn_mfma_f64_16x16x4f64(a1, bv, acc[1][nt], 0, 0, 0);
            }
        }
        if (q < 287) {
            #pragma unroll
            for (int j = 0; j < 4; ++j) BsF[cur ^ 1][tid + (j << 8)] = vbf[j];
            #pragma unroll
            for (int j = 0; j < 8; ++j) a_cur[j] = vaf[j];
            __syncthreads();   // single barrier: publishes buf cur^1 for iter q+1
        }
    }

    // epilogue: bias + ReLU, store f64, indexed by PROBED (rr,cc)
    #pragma unroll
    for (int mt = 0; mt < 2; ++mt) {
        #pragma unroll
        for (int g = 0; g < 4; ++g) {
            int co = co0 + (w << 5) + (mt << 4) + rr[g];
            double bs = (double)bias[co];
            double* row = t + ((size_t)b * 512 + co) * NPX;
            #pragma unroll
            for (int nt = 0; nt < 4; ++nt) {
                int pp = px0 + (nt << 4) + cc[g];
                if (pp < NPX) {
                    double v = acc[mt][nt][g] + bs;
                    row[pp] = v > 0.0 ? v : 0.0;
                }
            }
        }
    }
}

// ============================================================
// Kernel 2a: 1x1 heads, split-K x4 partials (f64)
// ============================================================
__global__ __launch_bounds__(64) void heads_partial_kernel(const double* __restrict__ t,
                                                           const float* __restrict__ cls_w,
                                                           const float* __restrict__ box_w,
                                                           double* __restrict__ part) {
    const int b = blockIdx.y, c = blockIdx.z;
    const int p = blockIdx.x * 64 + threadIdx.x;
    if (p >= NPX) return;
    const double* tb = t + ((size_t)b * 512 + c * 128) * NPX + p;

    double ac[9]  = {};
    double ab[36] = {};
    for (int ci = 0; ci < 128; ++ci) {
        double tv = tb[(size_t)ci * NPX];
        int cw = c * 128 + ci;
        #pragma unroll
        for (int o = 0; o < 9;  ++o) ac[o] = fma((double)cls_w[o * 512 + cw], tv, ac[o]);
        #pragma unroll
        for (int o = 0; o < 36; ++o) ab[o] = fma((double)box_w[o * 512 + cw], tv, ab[o]);
    }
    double* dst = part + ((size_t)(c * 8 + b) * 45) * NPX + p;
    #pragma unroll
    for (int o = 0; o < 9;  ++o) dst[(size_t)o * NPX] = ac[o];
    #pragma unroll
    for (int o = 0; o < 36; ++o) dst[(size_t)(9 + o) * NPX] = ab[o];
}

// shared decode body
__device__ __forceinline__ void decode_px(int b, int p, const double* s45,
                                          const float* cls_b, const float* box_b,
                                          float* out_obj, float* out_del,
                                          float* boxes, u64* items) {
    float* ob = out_obj + (size_t)b * NANCH + (size_t)p * 9;
    float* dl = out_del + (size_t)b * NANCH * 4 + (size_t)p * 36;
    const int yy = p / 76, xx = p - yy * 76;

    #pragma unroll
    for (int a = 0; a < 9; ++a) {
        double s  = s45[a] + (double)cls_b[a];
        ob[a] = (float)s;
        double d0 = s45[9 + 4*a + 0] + (double)box_b[4*a+0];
        double d1 = s45[9 + 4*a + 1] + (double)box_b[4*a+1];
        double d2 = s45[9 + 4*a + 2] + (double)box_b[4*a+2];
        double d3 = s45[9 + 4*a + 3] + (double)box_b[4*a+3];
        dl[4*a+0] = (float)d0; dl[4*a+1] = (float)d1;
        dl[4*a+2] = (float)d2; dl[4*a+3] = (float)d3;

        int si = a / 3, ri = a - si * 3;
        double sz = (si == 0) ? 128.0 : ((si == 1) ? 256.0 : 512.0);
        double hr = (ri == 0) ? 0.7071067811865476 : ((ri == 1) ? 1.0 : 1.4142135623730951);
        float bx2f = (float)(sz / hr * 0.5);
        float by2f = (float)(sz * hr * 0.5);

        double sx = (double)(xx * 16), sy = (double)(yy * 16);
        double x1 = sx - (double)bx2f, x2 = sx + (double)bx2f;
        double y1 = sy - (double)by2f, y2 = sy + (double)by2f;

        double wa = x2 - x1, ha = y2 - y1;
        double cxa = x1 + 0.5 * wa, cya = y1 + 0.5 * ha;
        double cx = d0 * wa + cxa, cy = d1 * ha + cya;
        double w  = exp(d2) * wa,  h  = exp(d3) * ha;

        double px1 = cx - 0.5 * w, py1 = cy - 0.5 * h;
        double px2 = cx + 0.5 * w, py2 = cy + 0.5 * h;
        px1 = fmin(fmax(px1, 0.0), 1216.0);
        py1 = fmin(fmax(py1, 0.0), 800.0);
        px2 = fmin(fmax(px2, 0.0), 1216.0);
        py2 = fmin(fmax(py2, 0.0), 800.0);

        bool keep = ((px2 - px1) >= 16.0) && ((py2 - py1) >= 16.0);
        double se = keep ? s : -INFINITY;

        u64 ubits = (u64)__double_as_longlong(se);
        u64 ka = (ubits >> 63) ? ~ubits : (ubits | 0x8000000000000000ull);
        u64 kd = ~ka;
        int n = p * 9 + a;
        items[(size_t)b * NANCH + n] = (kd & ~0xFFFFull) | (u64)(u32)n;
        *(float4*)(boxes + ((size_t)b * NANCH + n) * 4) =
            make_float4((float)px1, (float)py1, (float)px2, (float)py2);
    }
}

// ============================================================
// Kernel 2b: reduce partials (c ascending, deterministic) + decode
// ============================================================
__global__ __launch_bounds__(64) void reduce_decode_kernel(const double* __restrict__ part,
                                                           const float* __restrict__ cls_b,
                                                           const float* __restrict__ box_b,
                                                           float* __restrict__ out_obj,
                                                           float* __restrict__ out_del,
                                                           float* __restrict__ boxes,
                                                           u64* __restrict__ items) {
    const int b = blockIdx.y;
    const int p = blockIdx.x * 64 + threadIdx.x;
    if (p >= NPX) return;
    double s45[45];
    #pragma unroll
    for (int o = 0; o < 45; ++o) {
        double s = part[((size_t)(0 * 8 + b) * 45 + o) * NPX + p];
        s += part[((size_t)(1 * 8 + b) * 45 + o) * NPX + p];
        s += part[((size_t)(2 * 8 + b) * 45 + o) * NPX + p];
        s += part[((size_t)(3 * 8 + b) * 45 + o) * NPX + p];
        s45[o] = s;
    }
    decode_px(b, p, s45, cls_b, box_b, out_obj, out_del, boxes, items);
}

// ============================================================
// Kernel 2-fallback: single-stage heads+decode (if ws too small)
// ============================================================
__global__ __launch_bounds__(256) void heads_decode_kernel(const double* __restrict__ t,
                                                           const float* __restrict__ cls_w,
                                                           const float* __restrict__ cls_b,
                                                           const float* __restrict__ box_w,
                                                           const float* __restrict__ box_b,
                                                           float* __restrict__ out_obj,
                                                           float* __restrict__ out_del,
                                                           float* __restrict__ boxes,
                                                           u64* __restrict__ items) {
    const int b = blockIdx.y;
    const int p = blockIdx.x * 256 + threadIdx.x;
    if (p >= NPX) return;
    const double* tb = t + (size_t)b * 512 * NPX + p;
    double s45[45];
    #pragma unroll
    for (int o = 0; o < 45; ++o) s45[o] = 0.0;
    for (int ci = 0; ci < 512; ++ci) {
        double tv = tb[(size_t)ci * NPX];
        #pragma unroll
        for (int o = 0; o < 9;  ++o) s45[o]     = fma((double)cls_w[o * 512 + ci], tv, s45[o]);
        #pragma unroll
        for (int o = 0; o < 36; ++o) s45[9 + o] = fma((double)box_w[o * 512 + ci], tv, s45[9 + o]);
    }
    decode_px(b, p, s45, cls_b, box_b, out_obj, out_del, boxes, items);
}

// ============================================================
// IoU > 0.7 test (f32, matches reference formula)
// ============================================================
__device__ __forceinline__ bool iou_gt(float4 A, float4 B, float areaA, float areaB) {
    float ix1 = fmaxf(A.x, B.x), iy1 = fmaxf(A.y, B.y);
    float ix2 = fminf(A.z, B.z), iy2 = fminf(A.w, B.w);
    float iw = fmaxf(ix2 - ix1, 0.0f), ih = fmaxf(iy2 - iy1, 0.0f);
    float inter = iw * ih;
    float uni = areaA + areaB - inter;
    float iou = (uni > 0.0f) ? (inter / uni) : 0.0f;
    return iou > 0.7f;
}

// ============================================================
// Kernel 3: fused top-6000 select + bitonic sort + serial-scan NMS
// ============================================================
__global__ __launch_bounds__(1024) void topk_nms_kernel(const u64* __restrict__ items,
                                                        const float* __restrict__ boxes,
                                                        float* __restrict__ out) {
    extern __shared__ u64 buf[];              // 8192 u64
    u32* hist = (u32*)buf;
    u32* scan = hist + 4096;
    u32* scal = hist + 5120;

    const int b   = blockIdx.x;
    const int tid = threadIdx.x;
    const u64* it = items + (size_t)b * NANCH;

    // ---- level-1 histogram on item bits 52..63
    #pragma unroll
    for (int i = 0; i < 4; ++i) hist[tid * 4 + i] = 0;
    __syncthreads();
    for (int i = tid; i < NANCH; i += 1024)
        atomicAdd(&hist[(u32)(it[i] >> 52)], 1);
    __syncthreads();

    u32 B1, cum1;
    {
        u32 c0 = hist[tid*4], c1 = hist[tid*4+1], c2 = hist[tid*4+2], c3 = hist[tid*4+3];
        u32 S = c0 + c1 + c2 + c3;
        scan[tid] = S;
        __syncthreads();
        for (int off = 1; off < 1024; off <<= 1) {
            u32 v = (tid >= off) ? scan[tid - off] : 0;
            __syncthreads();
            scan[tid] += v;
            __syncthreads();
        }
        u32 excl = scan[tid] - S;
        const u32 target = 5999;
        if (target >= excl && target < excl + S) {
            u32 pfx = excl, bidx, cum;
            if      (target < pfx + c0)           { bidx = tid*4;   cum = pfx; }
            else if (target < pfx + c0 + c1)      { bidx = tid*4+1; cum = pfx + c0; }
            else if (target < pfx + c0 + c1 + c2) { bidx = tid*4+2; cum = pfx + c0 + c1; }
            else                                  { bidx = tid*4+3; cum = pfx + c0 + c1 + c2; }
            scal[0] = bidx; scal[1] = cum;
        }
    }
    __syncthreads();
    B1 = scal[0]; cum1 = scal[1];
    __syncthreads();

    // ---- level-2 histogram on item bits 40..51, within bin B1
    #pragma unroll
    for (int i = 0; i < 4; ++i) hist[tid * 4 + i] = 0;
    __syncthreads();
    for (int i = tid; i < NANCH; i += 1024) {
        u64 v = it[i];
        if ((u32)(v >> 52) == B1)
            atomicAdd(&hist[(u32)(v >> 40) & 0xFFF], 1);
    }
    __syncthreads();

    u32 B2;
    {
        u32 c0 = hist[tid*4], c1 = hist[tid*4+1], c2 = hist[tid*4+2], c3 = hist[tid*4+3];
        u32 S = c0 + c1 + c2 + c3;
        scan[tid] = S;
        __syncthreads();
        for (int off = 1; off < 1024; off <<= 1) {
            u32 v = (tid >= off) ? scan[tid - off] : 0;
            __syncthreads();
            scan[tid] += v;
            __syncthreads();
        }
        u32 excl = scan[tid] - S;
        const u32 target = 5999 - cum1;
        if (target >= excl && target < excl + S) {
            u32 pfx = excl, bidx;
            if      (target < pfx + c0)           bidx = tid*4;
            else if (target < pfx + c0 + c1)      bidx = tid*4+1;
            else if (target < pfx + c0 + c1 + c2) bidx = tid*4+2;
            else                                  bidx = tid*4+3;
            scal[2] = bidx;
        }
    }
    __syncthreads();
    B2 = scal[2];
    const u32 T = ((B1 << 12) | B2) + 1;
    __syncthreads();

    // ---- compaction (pad = ~0)
    for (int i = tid; i < 8192; i += 1024) buf[i] = ~0ull;
    __syncthreads();
    u32* cnt = (u32*)&buf[8191];
    if (tid == 0) *cnt = 0;
    __syncthreads();
    for (int i = tid; i < NANCH; i += 1024) {
        u64 v = it[i];
        if ((u32)(v >> 40) < T) {
            u32 pos = atomicAdd(cnt, 1);
            if (pos < 8191) buf[pos] = v;
        }
    }
    __syncthreads();
    if (tid == 0) buf[8191] = ~0ull;
    __syncthreads();

    // ---- bitonic sort 8192 u64 ascending (keys unique -> deterministic)
    for (int size = 2; size <= 8192; size <<= 1) {
        for (int stride = size >> 1; stride > 0; stride >>= 1) {
            #pragma unroll
            for (int v = 0; v < 4; ++v) {
                int idx = tid + (v << 10);
                int i = 2 * idx - (idx & (stride - 1));
                int j = i + stride;
                bool up = ((i & size) == 0);
                u64 x = buf[i], y = buf[j];
                if ((x > y) == up) { buf[i] = y; buf[j] = x; }
            }
            __syncthreads();
        }
    }

    // ---- pull my 6 chunk-candidates into registers
    float4 bx6[6]; u32 dead6[6];
    #pragma unroll
    for (int s = 0; s < 6; ++s) {
        int r = tid + (s << 10);
        u64 v = buf[r];
        bool dd = (r >= NSEL) || ((u32)(v >> 32) >= 0xFFF00000u);
        float4 bb = make_float4(0.f, 0.f, 0.f, 0.f);
        if (!dd) {
            u32 n = (u32)(v & 0xFFFFull);
            bb = *(const float4*)(boxes + ((size_t)b * NANCH + n) * 4);
        }
        bx6[s] = bb;
        dead6[s] = dd ? 1u : 0u;
    }
    __syncthreads();   // done with sorted buf -> reuse as NMS scratch

    float4* candbox = (float4*)buf;            // [1024]
    u64*    wmask   = (u64*)(buf + 2560);      // [16]
    float4* accb    = (float4*)(buf + 3072);   // [304]
    u32*    cntp    = (u32*)(buf + 3712);
    if (tid == 0) *cntp = 0;
    __syncthreads();

    // ---- serial-scan greedy NMS (accept iff no earlier accept IoU>0.7)
    for (int s = 0; s < 6; ++s) {
        int count = (int)*cntp;                // uniform
        if (count >= NOUT) break;
        float4 mb = bx6[s];
        float  ma = (mb.z - mb.x) * (mb.w - mb.y);
        bool dd = dead6[s] != 0;
        for (int a2 = 0; a2 < count && !dd; ++a2) {
            float4 abx = accb[a2];             // broadcast read
            if (iou_gt(mb, abx, ma, (abx.z - abx.x) * (abx.w - abx.y))) dd = true;
        }
        candbox[tid] = mb;
        u64 bal = __ballot(!dd);
        if ((tid & 63) == 0) wmask[tid >> 6] = bal;
        __syncthreads();
        if (tid < 64) {                        // wave 0 serializes survivors in rank order
            int cnt2 = count;
            for (int w2 = 0; w2 < 16 && cnt2 < NOUT; ++w2) {
                u64 mm = wmask[w2];
                while (mm != 0 && cnt2 < NOUT) {
                    int bit = __ffsll(mm) - 1;
                    mm &= (mm - 1);
                    float4 cb = candbox[(w2 << 6) + bit];
                    float  ca = (cb.z - cb.x) * (cb.w - cb.y);
                    bool okc = true;
                    for (int base = count; base < cnt2 && okc; base += 64) {
                        int idx = base + tid;
                        bool bad = false;
                        if (idx < cnt2) {
                            float4 abx = accb[idx];
                            bad = iou_gt(cb, abx, ca, (abx.z - abx.x) * (abx.w - abx.y));
                        }
                        if (__any(bad)) okc = false;
                    }
                    if (okc) {
                        if (tid == 0) accb[cnt2] = cb;
                        cnt2++;
                    }
                }
            }
            if (tid == 0) *cntp = (u32)cnt2;
        }
        __syncthreads();
    }

    int fin = (int)*cntp;
    for (int r = tid; r < NOUT; r += 1024) {
        float4 v = (r < fin) ? accb[r] : make_float4(0.f, 0.f, 0.f, 0.f);
        *(float4*)(out + ((size_t)b * NOUT + r) * 4) = v;
    }
}

// ============================================================
extern "C" void kernel_launch(void* const* d_in, const int* in_sizes, int n_in,
                              void* d_out, int out_size, void* d_ws, size_t ws_size,
                              hipStream_t stream) {
    const float* feat   = (const float*)d_in[0];
    const float* conv_w = (const float*)d_in[1];
    const float* conv_b = (const float*)d_in[2];
    const float* cls_w  = (const float*)d_in[3];
    const float* cls_b  = (const float*)d_in[4];
    const float* box_w  = (const float*)d_in[5];
    const float* box_b  = (const float*)d_in[6];

    float* out       = (float*)d_out;
    float* out_props = out;                       // [8][300][4]
    float* out_obj   = out + 9600;                // [8][34200]
    float* out_del   = out + 9600 + 273600;       // [8][34200][4]

    char* ws = (char*)d_ws;
    double* t      = (double*)(ws + OFF_T);
    float*  wt     = (float*)(ws + OFF_WT);
    float*  boxes  = (float*)(ws + OFF_BOXES);
    u64*    items  = (u64*)(ws + OFF_ITEMS);
    double* part   = (double*)(ws + OFF_PART);

    hipLaunchKernelGGL(wtrans_kernel, dim3(2304), dim3(1024), 0, stream, conv_w, wt);
    hipLaunchKernelGGL(conv3x3_mfma_kernel, dim3(60, 4, 8), dim3(256), 0, stream,
                       feat, wt, conv_b, t);
    if (ws_size >= WS_NEED_SPLIT) {
        hipLaunchKernelGGL(heads_partial_kernel, dim3(60, 8, 4), dim3(64), 0, stream,
                           t, cls_w, box_w, part);
        hipLaunchKernelGGL(reduce_decode_kernel, dim3(60, 8), dim3(64), 0, stream,
                           part, cls_b, box_b, out_obj, out_del, boxes, items);
    } else {
        hipLaunchKernelGGL(heads_decode_kernel, dim3(15, 8), dim3(256), 0, stream,
                           t, cls_w, cls_b, box_w, box_b, out_obj, out_del, boxes, items);
    }
    hipLaunchKernelGGL(topk_nms_kernel, dim3(8), dim3(1024), 65536, stream,
                       items, boxes, out_props);
}